// Round 9
// baseline (541.761 us; speedup 1.0000x reference)
//
#include <hip/hip_runtime.h>
#include <math.h>

#define D 128
#define NG 1024          // graphs
#define NB 512           // total blocks = 2 per CU, single dispatch round

typedef __bf16 bf16x8 __attribute__((ext_vector_type(8)));
typedef float f32x4 __attribute__((ext_vector_type(4)));

#define MFMA __builtin_amdgcn_mfma_f32_16x16x32_bf16

// lgkm-only barrier: does NOT drain vmcnt, so prefetched global loads stay in
// flight across tile boundaries. sched_barrier(0) fences per rule #18.
__device__ __forceinline__ void bar_lds() {
    __builtin_amdgcn_sched_barrier(0);
    asm volatile("s_waitcnt lgkmcnt(0)" ::: "memory");
    __builtin_amdgcn_s_barrier();
    __builtin_amdgcn_sched_barrier(0);
}

// two f32 -> packed bf16 dword (RNE)
__device__ __forceinline__ unsigned pk2(float a, float b) {
    union { __bf16 h[2]; unsigned u; } x;
    x.h[0] = (__bf16)a; x.h[1] = (__bf16)b;
    return x.u;
}

__device__ __forceinline__ int lbound(const int* __restrict__ a, int L, int v) {
    int lo = 0, hi = L;
    while (lo < hi) { int m = (lo + hi) >> 1; if (a[m] < v) lo = m + 1; else hi = m; }
    return lo;
}

// BCE(sigmoid(z), ta) with torch -100 log clamps ==
//   ta*min(sp(-z),100) + (1-ta)*min(sp(z),100),  sp(z)=max(z,0)+log1p(exp(-|z|)).
__device__ __forceinline__ float softplus_neg_abs(float az) {
    return __logf(1.f + __expf(-az));
}

// Wave-level segmented atomic accumulate; all 64 lanes converged.
__device__ __forceinline__ void seg_atomic(float* __restrict__ seg, int g, float v, bool valid) {
    float tv = valid ? v : 0.f;
    float s = tv;
#pragma unroll
    for (int o = 1; o < 64; o <<= 1) s += __shfl_xor(s, o, 64);
    unsigned long long vb = __ballot(valid);
    if (vb == 0ULL) return;
    int g0 = __shfl(g, __ffsll((unsigned long long)vb) - 1, 64);
    unsigned long long ub = __ballot((!valid) || (g == g0));
    const int lane = (int)(threadIdx.x & 63u);
    if (ub == ~0ULL) {
        if (lane == 0) atomicAdd(seg + g0, s);
    } else {
        if (valid) atomicAdd(seg + g, tv);
    }
}

__device__ __forceinline__ void wave_add(float* __restrict__ dst, float v) {
    float s = v;
#pragma unroll
    for (int o = 1; o < 64; o <<= 1) s += __shfl_xor(s, o, 64);
    if ((threadIdx.x & 63u) == 0) atomicAdd(dst, s);
}

// ---------------------------------------------------------------------------
// shared layout (floats), double-buffered for the 1-barrier pipeline:
// As0 0..4096 | As1 4096..8192 | Hb0 8192..12544 | Hb1 12544..16896
// P0 16896..17408 | P1 17408..17920 | W2s 17920..18944 | b2s 18944 | be2s 18952
#define OFF_AS0 0
#define OFF_AS1 4096
#define OFF_HB0 8192
#define OFF_HB1 12544
#define OFF_P0  16896
#define OFF_P1  17408
#define OFF_W2  17920
#define OFF_B2  18944
#define OFF_BE2 18952
#define SMEM_F  18956     // 75824 B -> 2 blocks/CU (register-capped anyway)

// A-slot swizzle: logical (blk=mt*4+kt, q, m) -> physical m' = (m&8)|((m^g)&7),
// g = kt + 4*(q>>1). Writer's 8 same-edge lanes (ks=0..7) map g to all 8 values
// (Latin square) -> conflict-free write phases. Readers use the same XOR.

template<int BF>
__device__ __forceinline__ void pack_tile(bool vE,
    const bf16x8& bs0, const bf16x8& bs1, const bf16x8& bd0, const bf16x8& bd1,
    const float4& rs0, const float4& rs1, const float4& rs2, const float4& rs3,
    const float4& rd0, const float4& rd1, const float4& rd2, const float4& rd3,
    uint4& u0, uint4& u1)
{
    if (vE) {
        if (BF) {
            float p[16];
#pragma unroll
            for (int i = 0; i < 8; i++) {
                p[i]     = fmaxf((float)bs0[i] * (float)bd0[i], 0.f);
                p[8 + i] = fmaxf((float)bs1[i] * (float)bd1[i], 0.f);
            }
            u0.x = pk2(p[0], p[1]);   u0.y = pk2(p[2], p[3]);
            u0.z = pk2(p[4], p[5]);   u0.w = pk2(p[6], p[7]);
            u1.x = pk2(p[8], p[9]);   u1.y = pk2(p[10], p[11]);
            u1.z = pk2(p[12], p[13]); u1.w = pk2(p[14], p[15]);
        } else {
            u0.x = pk2(fmaxf(rs0.x * rd0.x, 0.f), fmaxf(rs0.y * rd0.y, 0.f));
            u0.y = pk2(fmaxf(rs0.z * rd0.z, 0.f), fmaxf(rs0.w * rd0.w, 0.f));
            u0.z = pk2(fmaxf(rs1.x * rd1.x, 0.f), fmaxf(rs1.y * rd1.y, 0.f));
            u0.w = pk2(fmaxf(rs1.z * rd1.z, 0.f), fmaxf(rs1.w * rd1.w, 0.f));
            u1.x = pk2(fmaxf(rs2.x * rd2.x, 0.f), fmaxf(rs2.y * rd2.y, 0.f));
            u1.y = pk2(fmaxf(rs2.z * rd2.z, 0.f), fmaxf(rs2.w * rd2.w, 0.f));
            u1.z = pk2(fmaxf(rs3.x * rd3.x, 0.f), fmaxf(rs3.y * rd3.y, 0.f));
            u1.w = pk2(fmaxf(rs3.z * rd3.z, 0.f), fmaxf(rs3.w * rd3.w, 0.f));
        }
    } else { u0.x = u0.y = u0.z = u0.w = 0u; u1 = u0; }
}

template<int BF>
__global__ __launch_bounds__(512, 4)
void fused_kernel(const float* __restrict__ x, const unsigned short* __restrict__ xb,
                  const float* __restrict__ attr,
                  const float* __restrict__ xm, const float* __restrict__ xs,
                  const float* __restrict__ W1, const float* __restrict__ b1,
                  const float* __restrict__ W2, const float* __restrict__ b2,
                  const float* __restrict__ We1, const float* __restrict__ be1,
                  const float* __restrict__ We2, const float* __restrict__ be2,
                  const int* __restrict__ ei, const int* __restrict__ ein,
                  const int* __restrict__ eib, const int* __restrict__ einb,
                  const int* __restrict__ batch,
                  float* __restrict__ ws, int E, int N, int ntiles)
{
    __shared__ float smem[SMEM_F];
    float* posSum = ws;
    float* negSum = ws + NG;
    float* klSum  = ws + 2 * NG;
    float* tot    = ws + 3 * NG;
    float* b2s  = smem + OFF_B2;
    float* be2s = smem + OFF_BE2;
    unsigned short* W2ls = (unsigned short*)(smem + OFF_W2);

    const int bid = (int)blockIdx.x;
    const int t   = (int)threadIdx.x;
    const int wv  = t >> 6;
    const int l   = t & 63;
    const int sub = l & 15;
    const int q   = l >> 4;

    // ---- unified per-wave B set: wave w owns cols w*16..w*16+16 of W1 and We1
    bf16x8 W1f[4], Ehi[4], Elo[4];

#pragma unroll
    for (int pass = 0; pass < 12; pass++) {
        const float* Wsrc = (pass < 4) ? W1 : We1;
        const int p  = (pass >= 8);
        const int kt = pass & 3;
        __syncthreads();
        {
            const int ct = t >> 6, ln = t & 63;
            const int n  = ct * 16 + (ln & 15);
            const int kb = kt * 32 + (ln >> 4) * 8;
            float f[8];
#pragma unroll
            for (int j = 0; j < 8; j++) {
                float v = Wsrc[(kb + j) * D + n];
                f[j] = p ? (v - (float)(__bf16)v) : v;
            }
            uint4 u;
            u.x = pk2(f[0], f[1]); u.y = pk2(f[2], f[3]);
            u.z = pk2(f[4], f[5]); u.w = pk2(f[6], f[7]);
            *(uint4*)((unsigned short*)smem + (ct * 64 + ln) * 8) = u;
        }
        __syncthreads();
        bf16x8 f0 = *(const bf16x8*)((unsigned short*)smem + (wv * 64 + l) * 8);
        if (pass < 4)      W1f[kt] = f0;
        else if (pass < 8) Ehi[kt] = f0;
        else               Elo[kt] = f0;
    }
    __syncthreads();
    // W2 fragments -> LDS (read only by wv<4 in layer-2; frees 16 regs)
    if (t < 256) {
        const int jt = t >> 6, l2 = t & 63;
        const int sb = l2 & 15, qq = l2 >> 4;
        const int kb = jt * 32 + qq * 8;
        uint4 u;
        if (sb < 7) {
            u.x = pk2(W2[(kb + 0) * 7 + sb], W2[(kb + 1) * 7 + sb]);
            u.y = pk2(W2[(kb + 2) * 7 + sb], W2[(kb + 3) * 7 + sb]);
            u.z = pk2(W2[(kb + 4) * 7 + sb], W2[(kb + 5) * 7 + sb]);
            u.w = pk2(W2[(kb + 6) * 7 + sb], W2[(kb + 7) * 7 + sb]);
        } else { u.x = u.y = u.z = u.w = 0u; }
        *(uint4*)(W2ls + t * 8) = u;
    }
    // per-lane scalar weights for this wave's 16-col slice
    const float b1w  = b1[wv * 16 + sub];
    const float be1w = be1[wv * 16 + sub];
    const float We2w = We2[wv * 16 + sub];
    if (t < 7) b2s[t] = b2[t];
    if (t == 7) be2s[0] = be2[0];
    __syncthreads();

    // swizzled reader offsets (per kt, lane-constant)
    int roff[4];
#pragma unroll
    for (int kt = 0; kt < 4; kt++) {
        const int g2 = kt + ((q >> 1) << 2);
        roff[kt] = (q * 16 + ((sub & 8) | ((sub ^ g2) & 7))) * 8;
    }
    // swizzled writer slot (lane-constant, offset within an As buffer)
    const int e_  = t >> 3, ks_ = t & 7;
    const int gw  = (ks_ >> 1) | ((ks_ & 1) << 2);
    const int wslOff = (((e_ >> 4) * 4 + (ks_ >> 1)) * 64
                     + ((ks_ & 1) * 2) * 16 + ((e_ & 8) | ((e_ ^ gw) & 7))) * 8;
    const int k0_ = ks_ * 16;
    const int scA = (sub < 7) ? sub : 6;   // clamped attr column

    // ---- pipelined phase lambdas -------------------------------------
    auto pos_layer1 = [&](int cur) {
        const unsigned short* AsC = (const unsigned short*)(smem + (cur ? OFF_AS1 : OFF_AS0));
        unsigned short* HbC = (unsigned short*)(smem + (cur ? OFF_HB1 : OFF_HB0));
        float* Pc = smem + (cur ? OFF_P1 : OFF_P0);
#pragma unroll
        for (int mt = 0; mt < 4; mt++) {
            const int ab = mt * 2048;
            bf16x8 a0 = *(const bf16x8*)(AsC + ab +        roff[0]);
            bf16x8 a1 = *(const bf16x8*)(AsC + ab +  512 + roff[1]);
            bf16x8 a2 = *(const bf16x8*)(AsC + ab + 1024 + roff[2]);
            bf16x8 a3 = *(const bf16x8*)(AsC + ab + 1536 + roff[3]);
            // W1 head, split 2+2 chains
            f32x4 c1a = {0.f, 0.f, 0.f, 0.f}, c1b = {0.f, 0.f, 0.f, 0.f};
            c1a = MFMA(a0, W1f[0], c1a, 0, 0, 0);
            c1b = MFMA(a2, W1f[2], c1b, 0, 0, 0);
            c1a = MFMA(a1, W1f[1], c1a, 0, 0, 0);
            c1b = MFMA(a3, W1f[3], c1b, 0, 0, 0);
            // We head, hi/lo as independent 4-chains
            f32x4 c2a = {0.f, 0.f, 0.f, 0.f}, c2b = {0.f, 0.f, 0.f, 0.f};
            c2a = MFMA(a0, Ehi[0], c2a, 0, 0, 0);
            c2b = MFMA(a0, Elo[0], c2b, 0, 0, 0);
            c2a = MFMA(a1, Ehi[1], c2a, 0, 0, 0);
            c2b = MFMA(a1, Elo[1], c2b, 0, 0, 0);
            c2a = MFMA(a2, Ehi[2], c2a, 0, 0, 0);
            c2b = MFMA(a2, Elo[2], c2b, 0, 0, 0);
            c2a = MFMA(a3, Ehi[3], c2a, 0, 0, 0);
            c2b = MFMA(a3, Elo[3], c2b, 0, 0, 0);
#pragma unroll
            for (int r = 0; r < 4; r++)
                *(__bf16*)(HbC + (mt * 16 + q * 4 + r) * 136 + wv * 16 + sub) =
                    (__bf16)fmaxf(c1a[r] + c1b[r] + b1w, 0.f);
            float zp0 = fmaxf(c2a[0] + c2b[0] + be1w, 0.f) * We2w;
            float zp1 = fmaxf(c2a[1] + c2b[1] + be1w, 0.f) * We2w;
            float zp2 = fmaxf(c2a[2] + c2b[2] + be1w, 0.f) * We2w;
            float zp3 = fmaxf(c2a[3] + c2b[3] + be1w, 0.f) * We2w;
#pragma unroll
            for (int o = 1; o < 16; o <<= 1) {
                zp0 += __shfl_xor(zp0, o, 64);
                zp1 += __shfl_xor(zp1, o, 64);
                zp2 += __shfl_xor(zp2, o, 64);
                zp3 += __shfl_xor(zp3, o, 64);
            }
            if (sub < 4) {
                float vv = (sub == 0) ? zp0 : (sub == 1) ? zp1 : (sub == 2) ? zp2 : zp3;
                Pc[(wv << 6) + (mt << 4) + (q << 2) + sub] = vv;
            }
        }
    };

    auto pos_layer2 = [&](int basePv, int pcur, const float* atrP, int gWP, float& lpAcc) {
        const unsigned short* HbP = (const unsigned short*)(smem + (pcur ? OFF_HB1 : OFF_HB0));
        const float* Pp = smem + (pcur ? OFF_P1 : OFF_P0);
        if (wv < 4) {
            f32x4 cSa = {0.f, 0.f, 0.f, 0.f}, cSb = {0.f, 0.f, 0.f, 0.f};
            {
                const unsigned short* hb = HbP + (wv * 16 + sub) * 136 + q * 8;
                bf16x8 h0 = *(const bf16x8*)(hb);
                bf16x8 h1 = *(const bf16x8*)(hb + 32);
                bf16x8 h2 = *(const bf16x8*)(hb + 64);
                bf16x8 h3 = *(const bf16x8*)(hb + 96);
                bf16x8 w0 = *(const bf16x8*)(W2ls +        l * 8);
                bf16x8 w1 = *(const bf16x8*)(W2ls +  512 + l * 8);
                bf16x8 w2 = *(const bf16x8*)(W2ls + 1024 + l * 8);
                bf16x8 w3 = *(const bf16x8*)(W2ls + 1536 + l * 8);
                cSa = MFMA(h0, w0, cSa, 0, 0, 0);
                cSb = MFMA(h2, w2, cSb, 0, 0, 0);
                cSa = MFMA(h1, w1, cSa, 0, 0, 0);
                cSb = MFMA(h3, w3, cSb, 0, 0, 0);
            }
            float bceP[4];
#pragma unroll
            for (int r = 0; r < 4; r++) {
                const int EiE = basePv + wv * 16 + q * 4 + r;
                const bool on = (sub < 7) && (EiE < E);
                const float z  = cSa[r] + cSb[r] + b2s[scA];
                const float ta = atrP[r];
                const float az  = fabsf(z);
                const float L   = softplus_neg_abs(az);
                const float spz = fminf(fmaxf(z, 0.f) + L, 100.f);
                const float spn = fminf(fmaxf(-z, 0.f) + L, 100.f);
                bceP[r] = on ? (ta * spn + (1.f - ta) * spz) : 0.f;
            }
#pragma unroll
            for (int o = 1; o < 16; o <<= 1)
#pragma unroll
                for (int r = 0; r < 4; r++)
                    bceP[r] += __shfl_xor(bceP[r], o, 64);
            const float lossSel = (sub == 0) ? bceP[0] : (sub == 1) ? bceP[1]
                                : (sub == 2) ? bceP[2] : bceP[3];
            const int EiW = basePv + wv * 16 + q * 4 + (sub & 3);
            const bool act = (sub < 4) && (EiW < E);
            seg_atomic(posSum, gWP, lossSel, act);
        } else {
            const int e2 = (wv - 4) * 16 + sub;
            const int EiP = basePv + e2;
            const bool vP = (EiP < E) && (q == 0);
            const float zp = Pp[e2] + Pp[64 + e2] + Pp[128 + e2] + Pp[192 + e2]
                           + Pp[256 + e2] + Pp[320 + e2] + Pp[384 + e2] + Pp[448 + e2]
                           + be2s[0];
            const float az = fabsf(zp);
            const float L  = softplus_neg_abs(az);
            const float lossP = vP ? fminf(fmaxf(-zp, 0.f) + L, 100.f) : 0.f;
            seg_atomic(posSum, gWP, lossP, vP);
            lpAcc += lossP;
        }
    };

    auto neg_layer1 = [&](int cur) {
        const unsigned short* AsC = (const unsigned short*)(smem + (cur ? OFF_AS1 : OFF_AS0));
        float* Pc = smem + (cur ? OFF_P1 : OFF_P0);
#pragma unroll
        for (int mt = 0; mt < 4; mt++) {
            const int ab = mt * 2048;
            bf16x8 a0 = *(const bf16x8*)(AsC + ab +        roff[0]);
            bf16x8 a1 = *(const bf16x8*)(AsC + ab +  512 + roff[1]);
            bf16x8 a2 = *(const bf16x8*)(AsC + ab + 1024 + roff[2]);
            bf16x8 a3 = *(const bf16x8*)(AsC + ab + 1536 + roff[3]);
            f32x4 c2a = {0.f, 0.f, 0.f, 0.f}, c2b = {0.f, 0.f, 0.f, 0.f};
            c2a = MFMA(a0, Ehi[0], c2a, 0, 0, 0);
            c2b = MFMA(a0, Elo[0], c2b, 0, 0, 0);
            c2a = MFMA(a1, Ehi[1], c2a, 0, 0, 0);
            c2b = MFMA(a1, Elo[1], c2b, 0, 0, 0);
            c2a = MFMA(a2, Ehi[2], c2a, 0, 0, 0);
            c2b = MFMA(a2, Elo[2], c2b, 0, 0, 0);
            c2a = MFMA(a3, Ehi[3], c2a, 0, 0, 0);
            c2b = MFMA(a3, Elo[3], c2b, 0, 0, 0);
            float zp0 = fmaxf(c2a[0] + c2b[0] + be1w, 0.f) * We2w;
            float zp1 = fmaxf(c2a[1] + c2b[1] + be1w, 0.f) * We2w;
            float zp2 = fmaxf(c2a[2] + c2b[2] + be1w, 0.f) * We2w;
            float zp3 = fmaxf(c2a[3] + c2b[3] + be1w, 0.f) * We2w;
#pragma unroll
            for (int o = 1; o < 16; o <<= 1) {
                zp0 += __shfl_xor(zp0, o, 64);
                zp1 += __shfl_xor(zp1, o, 64);
                zp2 += __shfl_xor(zp2, o, 64);
                zp3 += __shfl_xor(zp3, o, 64);
            }
            if (sub < 4) {
                float vv = (sub == 0) ? zp0 : (sub == 1) ? zp1 : (sub == 2) ? zp2 : zp3;
                Pc[(wv << 6) + (mt << 4) + (q << 2) + sub] = vv;
            }
        }
    };

    auto neg_tail = [&](int basePv, int pcur, int gNP, float& lnAcc) {
        if (wv != 0) return;
        const float* Pp = smem + (pcur ? OFF_P1 : OFF_P0);
        const bool valid = (basePv + l < E);
        float zp = be2s[0];
#pragma unroll
        for (int i = 0; i < 8; i++) zp += Pp[i * 64 + l];
        float lossN = 0.f;
        if (valid) {
            const float az = fabsf(zp);
            const float L  = softplus_neg_abs(az);
            lossN = fminf(fmaxf(zp, 0.f) + L, 100.f);
        }
        seg_atomic(negSum, gNP, lossN, valid);
        lnAcc += valid ? lossN : 0.f;
    };

    // =====================================================================
    // POS loop: 1 barrier/tile; layer2 of tile t-1 runs after barrier t
    // =====================================================================
    {
        float lpAcc = 0.f;
        float4 rs0, rs1, rs2, rs3, rd0, rd1, rd2, rd3;
        bf16x8 bs0, bs1, bd0, bd1;
        int sN, dN;
        float atrP[4] = {0.f, 0.f, 0.f, 0.f};
        int gWP = 0, basePrev = 0, lastCur = 0;
        int tile = bid;
        {   // prologue: x-regs tile0, idx tile1
            int ix = tile * 64 + e_; ix = ix < E ? ix : E - 1;
            const int s0 = ei[ix], d0 = ei[E + ix];
            if (BF) {
                const bf16x8* ps = (const bf16x8*)(xb + (size_t)s0 * D + k0_);
                const bf16x8* pd = (const bf16x8*)(xb + (size_t)d0 * D + k0_);
                bs0 = ps[0]; bs1 = ps[1]; bd0 = pd[0]; bd1 = pd[1];
            } else {
                const float4* ps = (const float4*)(x + (size_t)s0 * D + k0_);
                const float4* pd = (const float4*)(x + (size_t)d0 * D + k0_);
                rs0 = ps[0]; rs1 = ps[1]; rs2 = ps[2]; rs3 = ps[3];
                rd0 = pd[0]; rd1 = pd[1]; rd2 = pd[2]; rd3 = pd[3];
            }
            int ix1 = (tile + NB < ntiles) ? (tile + NB) * 64 + e_ : 0;
            ix1 = ix1 < E ? ix1 : E - 1;
            sN = ei[ix1]; dN = ei[E + ix1];
        }
        for (int it = 0; tile < ntiles; ++it, tile += NB) {
            const int cur = it & 1;
            const int base = tile * 64;
            // A: pack current tile into As[cur]
            unsigned short* AsW = (unsigned short*)(smem + (cur ? OFF_AS1 : OFF_AS0));
            uint4 u0, u1;
            pack_tile<BF>(base + e_ < E, bs0, bs1, bd0, bd1,
                          rs0, rs1, rs2, rs3, rd0, rd1, rd2, rd3, u0, u1);
            *(uint4*)(AsW + wslOff) = u0;
            *(uint4*)(AsW + wslOff + 128) = u1;
            // B: prefetch next tile's x rows + next-next indices
            if (tile + NB < ntiles) {
                if (BF) {
                    const bf16x8* ps = (const bf16x8*)(xb + (size_t)sN * D + k0_);
                    const bf16x8* pd = (const bf16x8*)(xb + (size_t)dN * D + k0_);
                    bs0 = ps[0]; bs1 = ps[1]; bd0 = pd[0]; bd1 = pd[1];
                } else {
                    const float4* ps = (const float4*)(x + (size_t)sN * D + k0_);
                    const float4* pd = (const float4*)(x + (size_t)dN * D + k0_);
                    rs0 = ps[0]; rs1 = ps[1]; rs2 = ps[2]; rs3 = ps[3];
                    rd0 = pd[0]; rd1 = pd[1]; rd2 = pd[2]; rd3 = pd[3];
                }
                if (tile + 2 * NB < ntiles) {
                    int ix2 = (tile + 2 * NB) * 64 + e_;
                    ix2 = ix2 < E ? ix2 : E - 1;
                    sN = ei[ix2]; dN = ei[E + ix2];
                }
            }
            // C: loss operands for THIS tile (consumed by layer2 next iteration)
            float atrN[4]; int gWN;
            if (wv < 4) {
#pragma unroll
                for (int r = 0; r < 4; r++) {
                    int EiE = base + wv * 16 + q * 4 + r;
                    EiE = EiE < E ? EiE : E - 1;
                    atrN[r] = attr[(size_t)EiE * 9 + scA];
                }
                int EiW = base + wv * 16 + q * 4 + (sub & 3);
                EiW = EiW < E ? EiW : E - 1;
                gWN = eib[EiW];
            } else {
                int EiP = base + (wv - 4) * 16 + sub;
                EiP = EiP < E ? EiP : E - 1;
                gWN = eib[EiP];
#pragma unroll
                for (int r = 0; r < 4; r++) atrN[r] = 0.f;
            }
            // D: the single barrier
            bar_lds();
            // E: layer2 of previous tile (buffers cur^1)
            if (it > 0) pos_layer2(basePrev, cur ^ 1, atrP, gWP, lpAcc);
            // F: layer1 of this tile (buffers cur)
            pos_layer1(cur);
            // shift
#pragma unroll
            for (int r = 0; r < 4; r++) atrP[r] = atrN[r];
            gWP = gWN; basePrev = base; lastCur = cur;
        }
        // epilogue: finish last tile's layer2
        bar_lds();
        pos_layer2(basePrev, lastCur, atrP, gWP, lpAcc);
        if (wv >= 4) wave_add(tot + 1, lpAcc);
    }

    // =====================================================================
    // NEG loop: same 1-barrier pipeline, We-head only
    // =====================================================================
    {
        float lnAcc = 0.f;
        float4 rs0, rs1, rs2, rs3, rd0, rd1, rd2, rd3;
        bf16x8 bs0, bs1, bd0, bd1;
        int sN, dN;
        int gNP = 0, basePrev = 0, lastCur = 0;
        int tile = bid;
        {
            int ix = tile * 64 + e_; ix = ix < E ? ix : E - 1;
            const int s0 = ein[ix], d0 = ein[E + ix];
            if (BF) {
                const bf16x8* ps = (const bf16x8*)(xb + (size_t)s0 * D + k0_);
                const bf16x8* pd = (const bf16x8*)(xb + (size_t)d0 * D + k0_);
                bs0 = ps[0]; bs1 = ps[1]; bd0 = pd[0]; bd1 = pd[1];
            } else {
                const float4* ps = (const float4*)(x + (size_t)s0 * D + k0_);
                const float4* pd = (const float4*)(x + (size_t)d0 * D + k0_);
                rs0 = ps[0]; rs1 = ps[1]; rs2 = ps[2]; rs3 = ps[3];
                rd0 = pd[0]; rd1 = pd[1]; rd2 = pd[2]; rd3 = pd[3];
            }
            int ix1 = (tile + NB < ntiles) ? (tile + NB) * 64 + e_ : 0;
            ix1 = ix1 < E ? ix1 : E - 1;
            sN = ein[ix1]; dN = ein[E + ix1];
        }
        for (int it = 0; tile < ntiles; ++it, tile += NB) {
            const int cur = it & 1;
            const int base = tile * 64;
            unsigned short* AsW = (unsigned short*)(smem + (cur ? OFF_AS1 : OFF_AS0));
            uint4 u0, u1;
            pack_tile<BF>(base + e_ < E, bs0, bs1, bd0, bd1,
                          rs0, rs1, rs2, rs3, rd0, rd1, rd2, rd3, u0, u1);
            *(uint4*)(AsW + wslOff) = u0;
            *(uint4*)(AsW + wslOff + 128) = u1;
            if (tile + NB < ntiles) {
                if (BF) {
                    const bf16x8* ps = (const bf16x8*)(xb + (size_t)sN * D + k0_);
                    const bf16x8* pd = (const bf16x8*)(xb + (size_t)dN * D + k0_);
                    bs0 = ps[0]; bs1 = ps[1]; bd0 = pd[0]; bd1 = pd[1];
                } else {
                    const float4* ps = (const float4*)(x + (size_t)sN * D + k0_);
                    const float4* pd = (const float4*)(x + (size_t)dN * D + k0_);
                    rs0 = ps[0]; rs1 = ps[1]; rs2 = ps[2]; rs3 = ps[3];
                    rd0 = pd[0]; rd1 = pd[1]; rd2 = pd[2]; rd3 = pd[3];
                }
                if (tile + 2 * NB < ntiles) {
                    int ix2 = (tile + 2 * NB) * 64 + e_;
                    ix2 = ix2 < E ? ix2 : E - 1;
                    sN = ein[ix2]; dN = ein[E + ix2];
                }
            }
            int gNN = 0;
            if (wv == 0) {
                int EiL = base + l;
                EiL = EiL < E ? EiL : E - 1;
                gNN = einb[EiL];
            }
            bar_lds();
            if (it > 0) neg_tail(basePrev, cur ^ 1, gNP, lnAcc);
            neg_layer1(cur);
            gNP = gNN; basePrev = base; lastCur = cur;
        }
        bar_lds();
        neg_tail(basePrev, lastCur, gNP, lnAcc);
        if (wv == 0) wave_add(tot + 2, lnAcc);
    }

    // =====================================================================
    // KL loop (no barriers)
    // =====================================================================
    {
        const int hf = l >> 5, li = l & 31;      // 2 rows / wave
        const int gwv = bid * 8 + wv;
        for (int rb = gwv * 2; rb < N; rb += NB * 16) {
            const int row = rb + hf;
            const bool v = (row < N);
            const int rr = v ? row : (N - 1);
            const float4 mm = *(const float4*)(xm + (size_t)rr * D + li * 4);
            const float4 ss = *(const float4*)(xs + (size_t)rr * D + li * 4);
            float a;
            a  = 1.f + 2.f * fmaxf(__logf(ss.x), -1e4f) - mm.x * mm.x - ss.x * ss.x;
            a += 1.f + 2.f * fmaxf(__logf(ss.y), -1e4f) - mm.y * mm.y - ss.y * ss.y;
            a += 1.f + 2.f * fmaxf(__logf(ss.z), -1e4f) - mm.z * mm.z - ss.z * ss.z;
            a += 1.f + 2.f * fmaxf(__logf(ss.w), -1e4f) - mm.w * mm.w - ss.w * ss.w;
#pragma unroll
            for (int o = 1; o < 32; o <<= 1) a += __shfl_xor(a, o, 64);
            if (li == 0 && v) {
                const int g = batch[row];
                atomicAdd(klSum + g, -0.5f * a);
            }
        }
    }
}

__global__ __launch_bounds__(256)
void conv_kernel(const float* __restrict__ x, unsigned short* __restrict__ xb, int n8) {
    const int i0 = (int)(blockIdx.x * 256 + threadIdx.x);
    const int stride = (int)(gridDim.x * 256);
    for (int j = i0; j < n8; j += stride) {
        const float4 a = ((const float4*)x)[(size_t)j * 2];
        const float4 b = ((const float4*)x)[(size_t)j * 2 + 1];
        uint4 u;
        u.x = pk2(a.x, a.y); u.y = pk2(a.z, a.w);
        u.z = pk2(b.x, b.y); u.w = pk2(b.z, b.w);
        ((uint4*)xb)[j] = u;
    }
}

__global__ __launch_bounds__(256)
void final_kernel(const int* __restrict__ eib, const int* __restrict__ einb,
                  const int* __restrict__ nbatch,
                  float* __restrict__ ws, int E, int N, int G) {
    const int g = (int)(blockIdx.x * blockDim.x + threadIdx.x);
    float lg = 0.f;
    if (g < G) {
        const int cP = lbound(eib, E, g + 1) - lbound(eib, E, g);
        const int cN = lbound(einb, E, g + 1) - lbound(einb, E, g);
        const int cB = lbound(nbatch, N, g + 1) - lbound(nbatch, N, g);
        const float fp = fmaxf((float)cP, 1.f);
        const float fn = fmaxf((float)cN, 1.f);
        const float fb = fmaxf((float)cB, 1.f);
        lg = ws[g] / fp + ws[NG + g] / fn + ws[2 * NG + g] / (fb * fb);
    }
#pragma unroll
    for (int o = 1; o < 64; o <<= 1) lg += __shfl_xor(lg, o, 64);
    if ((threadIdx.x & 63u) == 0) atomicAdd(ws + 3 * NG, lg);
}

__global__ void out_kernel(const float* __restrict__ ws, float* __restrict__ out,
                           int E, int G) {
    if (threadIdx.x == 0 && blockIdx.x == 0) {
        out[0] = ws[3 * NG] / (float)G;
        out[1] = 0.5f * (ws[3 * NG + 1] / (float)E + ws[3 * NG + 2] / (float)E);
    }
}

extern "C" void kernel_launch(void* const* d_in, const int* in_sizes, int n_in,
                              void* d_out, int out_size, void* d_ws, size_t ws_size,
                              hipStream_t stream) {
    const float* x    = (const float*)d_in[0];
    const float* attr = (const float*)d_in[1];
    const float* xm   = (const float*)d_in[2];
    const float* xsd  = (const float*)d_in[3];
    const float* W1   = (const float*)d_in[4];
    const float* b1   = (const float*)d_in[5];
    const float* W2   = (const float*)d_in[6];
    const float* b2   = (const float*)d_in[7];
    const float* We1  = (const float*)d_in[8];
    const float* be1  = (const float*)d_in[9];
    const float* We2  = (const float*)d_in[10];
    const float* be2  = (const float*)d_in[11];
    const int* ei     = (const int*)d_in[12];
    const int* ein    = (const int*)d_in[13];
    const int* eib    = (const int*)d_in[14];
    const int* einb   = (const int*)d_in[15];
    const int* batch  = (const int*)d_in[16];

    const int N = in_sizes[0] / D;       // 100000
    const int E = in_sizes[14];          // 600000
    const int G = 1024;

    float* ws = (float*)d_ws;
    unsigned short* xb = (unsigned short*)(ws + 3 * NG + 8);   // 16B-aligned
    const size_t need = (size_t)(3 * NG + 8) * sizeof(float)
                      + (size_t)N * D * sizeof(unsigned short);

    hipMemsetAsync(d_ws, 0, (size_t)(3 * NG + 4) * sizeof(float), stream);

    const int ntiles = (E + 63) / 64;
    if (ws_size >= need) {
        conv_kernel<<<2048, 256, 0, stream>>>(x, xb, N * D / 8);
        fused_kernel<1><<<NB, 512, 0, stream>>>(x, xb, attr, xm, xsd,
                                                W1, b1, W2, b2, We1, be1, We2, be2,
                                                ei, ein, eib, einb, batch,
                                                ws, E, N, ntiles);
    } else {
        fused_kernel<0><<<NB, 512, 0, stream>>>(x, xb, attr, xm, xsd,
                                                W1, b1, W2, b2, We1, be1, We2, be2,
                                                ei, ein, eib, einb, batch,
                                                ws, E, N, ntiles);
    }
    final_kernel<<<(G + 255) / 256, 256, 0, stream>>>(eib, einb, batch,
                                                      ws, E, N, G);
    out_kernel<<<1, 64, 0, stream>>>(ws, (float*)d_out, E, G);
}